// Round 2
// baseline (251.549 us; speedup 1.0000x reference)
//
#include <hip/hip_runtime.h>

#define WIDTH  1024
#define HEIGHT 1024

__global__ __launch_bounds__(256) void fdtd_kernel(
    const float* __restrict__ u1,
    const float* __restrict__ u0,
    const float* __restrict__ j2,
    const float* __restrict__ j0,
    float* __restrict__ out,
    int nrows)
{
    const int row = blockIdx.x;                 // global row across B*H
    if (row >= nrows) return;
    const int y  = row & (HEIGHT - 1);          // row within image
    const int x0 = threadIdx.x << 2;            // 4 floats per thread, 16B aligned
    const long base = (long)row * WIDTH + x0;

    // 16B vector loads
    const float4 c   = *(const float4*)(u1 + base);
    const float4 a0  = *(const float4*)(u0 + base);
    const float4 b2  = *(const float4*)(j2 + base);
    const float4 b0  = *(const float4*)(j0 + base);
    float4 up = make_float4(0.f, 0.f, 0.f, 0.f);
    float4 dn = make_float4(0.f, 0.f, 0.f, 0.f);
    if (y > 0)          up = *(const float4*)(u1 + base - WIDTH);
    if (y < HEIGHT - 1) dn = *(const float4*)(u1 + base + WIDTH);

    // x-edge neighbors (zero padding at image borders)
    const float left  = (x0 > 0)         ? u1[base - 1] : 0.0f;
    const float right = (x0 + 4 < WIDTH) ? u1[base + 4] : 0.0f;

    const float cf[4]  = {c.x,  c.y,  c.z,  c.w};
    const float u0f[4] = {a0.x, a0.y, a0.z, a0.w};
    const float j2f[4] = {b2.x, b2.y, b2.z, b2.w};
    const float j0f[4] = {b0.x, b0.y, b0.z, b0.w};
    const float upf[4] = {up.x, up.y, up.z, up.w};
    const float dnf[4] = {dn.x, dn.y, dn.z, dn.w};

    float o[4];
#pragma unroll
    for (int i = 0; i < 4; ++i) {
        const float l = (i == 0) ? left  : cf[i - 1];
        const float r = (i == 3) ? right : cf[i + 1];
        const float lap = upf[i] + dnf[i] + l + r - 4.0f * cf[i];
        o[i] = 2.0f * cf[i] - u0f[i]
             + 0.25f * lap
             - 0.0025f * (j2f[i] - j0f[i]);
    }
    *(float4*)(out + base) = make_float4(o[0], o[1], o[2], o[3]);
}

extern "C" void kernel_launch(void* const* d_in, const int* in_sizes, int n_in,
                              void* d_out, int out_size, void* d_ws, size_t ws_size,
                              hipStream_t stream) {
    const float* u1 = (const float*)d_in[0];
    const float* u0 = (const float*)d_in[1];
    const float* j2 = (const float*)d_in[2];
    const float* j0 = (const float*)d_in[3];
    float* out = (float*)d_out;

    const int nrows = out_size / WIDTH;         // B*H = 16384
    dim3 block(WIDTH / 4);                      // 256 threads, one row per block
    dim3 grid(nrows);                           // 16384 blocks
    fdtd_kernel<<<grid, block, 0, stream>>>(u1, u0, j2, j0, out, nrows);
}